// Round 4
// baseline (576.394 us; speedup 1.0000x reference)
//
#include <hip/hip_runtime.h>
#include <hip/hip_fp16.h>

// Problem constants
#define OUT_F 4096
#define IN_F  4096
#define M_TOTAL 8192          // 4 * 2048
#define TOTAL_W (OUT_F * IN_F)

typedef _Float16 f16x8 __attribute__((ext_vector_type(8)));
typedef float    f32x16 __attribute__((ext_vector_type(16)));

__device__ const float NF4_LUT_C[16] = {
    -1.0f, -0.6961928009986877f, -0.5250730514526367f, -0.39491748809814453f,
    -0.28444138169288635f, -0.18477343022823334f, -0.09105003625154495f, 0.0f,
    0.07958029955625534f, 0.16093020141124725f, 0.24611230194568634f,
    0.33791524171829224f, 0.44070982933044434f, 0.5626170039176941f,
    0.7229568362236023f, 1.0f};

// ---------------- Dequant: indices + q_scales -> W fp16 [OUT_F][IN_F] ----------------
__global__ __launch_bounds__(256) void k_dequant(const int* __restrict__ idx,
                                                 const int* __restrict__ qs,
                                                 _Float16* __restrict__ W) {
    __shared__ float slut[16];
    if (threadIdx.x < 16) slut[threadIdx.x] = NF4_LUT_C[threadIdx.x];
    __syncthreads();
    int t = blockIdx.x * 256 + threadIdx.x;              // 0 .. TOTAL_W/8-1
    const int4* ip = (const int4*)idx;
    int4 a = ip[2 * t];
    int4 b = ip[2 * t + 1];
    // exact reference order: (q/127)*0.05 in fp32, then vals*absmax, then fp16 cast
    float absmax = ((float)qs[t >> 3] / 127.0f) * 0.05f;
    f16x8 o;
    o[0] = (_Float16)(slut[a.x] * absmax);
    o[1] = (_Float16)(slut[a.y] * absmax);
    o[2] = (_Float16)(slut[a.z] * absmax);
    o[3] = (_Float16)(slut[a.w] * absmax);
    o[4] = (_Float16)(slut[b.x] * absmax);
    o[5] = (_Float16)(slut[b.y] * absmax);
    o[6] = (_Float16)(slut[b.z] * absmax);
    o[7] = (_Float16)(slut[b.w] * absmax);
    *(f16x8*)(W + (size_t)t * 8) = o;
}

// ---------------- Cast X fp32 -> fp16 ----------------
__global__ __launch_bounds__(256) void k_cast(const float* __restrict__ x,
                                              _Float16* __restrict__ xh) {
    int t = blockIdx.x * 256 + threadIdx.x;              // 8 elems per thread
    const float4* xp = (const float4*)x;
    float4 a = xp[2 * t];
    float4 b = xp[2 * t + 1];
    f16x8 o;
    o[0] = (_Float16)a.x; o[1] = (_Float16)a.y; o[2] = (_Float16)a.z; o[3] = (_Float16)a.w;
    o[4] = (_Float16)b.x; o[5] = (_Float16)b.y; o[6] = (_Float16)b.z; o[7] = (_Float16)b.w;
    *(f16x8*)(xh + (size_t)t * 8) = o;
}

// ---------------- GEMM: C[M][N] = A[M][K] * B[N][K]^T ----------------
// Block tile 256x128, 4 waves stacked in M, each wave 64x128 via 2x4 of
// 32x32x16 MFMA (fragment reuse: A x4, B x2 -> 0.75 KB LDS/MFMA vs 1.0).
// BK=64 stored as TWO k32 panels, each [rows][32 halves] (64-B row stride) —
// this replicates round 2's measured-conflict-free bank geometry exactly.
// Swizzle within a panel: logical k-chunk kk (0..3) at row r lives at
// pos = kk ^ ((r>>1)&3).  Staging permutes the GLOBAL k offset (LDS dest
// stays lane-contiguous for global_load_lds).

__device__ __forceinline__ void async16(const _Float16* g, _Float16* l) {
    __builtin_amdgcn_global_load_lds(
        (const __attribute__((address_space(1))) void*)g,
        (__attribute__((address_space(3))) void*)l,
        16, 0, 0);
}

__global__ __launch_bounds__(256, 2) void k_gemm(const _Float16* __restrict__ A,
                                                 const _Float16* __restrict__ B,
                                                 float* __restrict__ C) {
    const int K = IN_F, N = OUT_F;
    __shared__ _Float16 sA[2 * 256 * 32];   // 32 KB: 2 panels x 256 rows x 32
    __shared__ _Float16 sB[2 * 128 * 32];   // 16 KB: 2 panels x 128 rows x 32

    const int tid = threadIdx.x;
    // Raster: 16-block super-groups = 4 M-tiles x 4 N-tiles (1024x512 out region)
    const int bid = blockIdx.x;             // 0..1023
    const int g   = bid >> 4;               // 64 groups, 8x8
    const int w16 = bid & 15;
    const int m0  = ((g >> 3) * 4 + (w16 >> 2)) * 256;
    const int n0  = ((g & 7) * 4 + (w16 & 3)) * 128;

    const int lane = tid & 63;
    const int wave = tid >> 6;              // wave covers rows wave*64..+64
    const int m    = lane & 31;             // mfma row/col within 32
    const int h    = lane >> 5;             // k-half selector
    const int msw  = (m >> 1) & 3;          // read-side swizzle term

    f32x16 acc[2][4];
#pragma unroll
    for (int i = 0; i < 2; i++)
#pragma unroll
        for (int j = 0; j < 4; j++)
#pragma unroll
            for (int r = 0; r < 16; r++) acc[i][j][r] = 0.f;

    // Staging: thread t fills 16-B chunks {j*256+t}.  Chunk c: panel/row/pos
    // decompose s.t. pos = t&3, row-in-panel = (jlow)*64 + (t>>2).
    // Global k-chunk = pos ^ ((row>>1)&3) = (t&3) ^ ((t>>3)&3)  (j-invariant).
    const int rr   = tid >> 2;                              // 0..63
    const int gpos = ((tid & 3) ^ ((tid >> 3) & 3)) * 8;    // global k elem offset
    const _Float16* aBase = A + (size_t)(m0 + rr) * K + gpos;
    const _Float16* bBase = B + (size_t)(n0 + rr) * K + gpos;
    _Float16* lAt = sA + (size_t)tid * 8;
    _Float16* lBt = sB + (size_t)tid * 8;

    for (int kt = 0; kt < K; kt += 64) {
        // sA: 2048 chunks -> 8/thread.  j=0..3 panel 0, j=4..7 panel 1;
        // row = (j&3)*64 + rr.
#pragma unroll
        for (int j = 0; j < 8; j++)
            async16(aBase + kt + (size_t)((j & 3) * 64) * K + (j >> 2) * 32,
                    lAt + j * 2048);
        // sB: 1024 chunks -> 4/thread.  j=0..1 panel 0, j=2..3 panel 1;
        // row = (j&1)*64 + rr.
#pragma unroll
        for (int j = 0; j < 4; j++)
            async16(bBase + kt + (size_t)((j & 1) * 64) * K + (j >> 1) * 32,
                    lBt + j * 2048);
        __syncthreads();   // drains vmcnt for global_load_lds

#pragma unroll
        for (int s = 0; s < 4; s++) {       // 4 k-steps of 16
            const int panel = s >> 1;
            const int pos   = ((2 * (s & 1) + h) ^ msw) * 8;
            f16x8 af[2], bf[4];
#pragma unroll
            for (int mi = 0; mi < 2; mi++)
                af[mi] = *(const f16x8*)&sA[panel * 8192 +
                                            (wave * 64 + mi * 32 + m) * 32 + pos];
#pragma unroll
            for (int ni = 0; ni < 4; ni++)
                bf[ni] = *(const f16x8*)&sB[panel * 4096 + (ni * 32 + m) * 32 + pos];
#pragma unroll
            for (int mi = 0; mi < 2; mi++)
#pragma unroll
                for (int ni = 0; ni < 4; ni++)
                    acc[mi][ni] = __builtin_amdgcn_mfma_f32_32x32x16_f16(
                        af[mi], bf[ni], acc[mi][ni], 0, 0, 0);
        }
        __syncthreads();   // protect LDS before next overwrite
    }

    // Epilogue: 32x32 C/D layout col=lane&31, row=(reg&3)+8*(reg>>2)+4*(lane>>5)
#pragma unroll
    for (int mi = 0; mi < 2; mi++)
#pragma unroll
        for (int ni = 0; ni < 4; ni++)
#pragma unroll
            for (int r = 0; r < 16; r++) {
                int row = m0 + wave * 64 + mi * 32 + (r & 3) + 8 * (r >> 2) + 4 * h;
                int col = n0 + ni * 32 + m;
                C[(size_t)row * N + col] = acc[mi][ni][r];
            }
}

extern "C" void kernel_launch(void* const* d_in, const int* in_sizes, int n_in,
                              void* d_out, int out_size, void* d_ws, size_t ws_size,
                              hipStream_t stream) {
    const float* x       = (const float*)d_in[0];
    const int*   indices = (const int*)d_in[1];
    const int*   qscales = (const int*)d_in[2];
    float*       out     = (float*)d_out;

    _Float16* W  = (_Float16*)d_ws;                                   // 32 MiB
    _Float16* Xh = (_Float16*)((char*)d_ws + (size_t)TOTAL_W * 2);    // 64 MiB

    k_dequant<<<TOTAL_W / 8 / 256, 256, 0, stream>>>(indices, qscales, W);
    k_cast<<<(size_t)M_TOTAL * IN_F / 8 / 256, 256, 0, stream>>>(x, Xh);

    k_gemm<<<1024, 256, 0, stream>>>(Xh, W, out);
}